// Round 4
// baseline (2619.521 us; speedup 1.0000x reference)
//
#include <hip/hip_runtime.h>

#define DEPTHL 4
#define NHEADS 8
#define DIMC 512
#define HIDDENC 1024
#define NTOK 17
#define NROWS (2048*NTOK)   // 34816

typedef __attribute__((ext_vector_type(8))) short s8v;
typedef __attribute__((ext_vector_type(4))) float f4v;
typedef __attribute__((ext_vector_type(4))) short s4v;

static __device__ __forceinline__ float bf2f(short s) {
  unsigned u = ((unsigned)(unsigned short)s) << 16;
  return __builtin_bit_cast(float, u);
}
static __device__ __forceinline__ short f2bf(float f) {
  unsigned u = __builtin_bit_cast(unsigned, f);
  u += 0x7fffu + ((u >> 16) & 1u);
  return (short)(u >> 16);
}

static __device__ __forceinline__ void load_lds16(const void* g, void* l) {
  __builtin_amdgcn_global_load_lds(
      (const __attribute__((address_space(1))) unsigned int*)g,
      (__attribute__((address_space(3))) unsigned int*)l, 16, 0, 0);
}

#define BARX() asm volatile("s_barrier" ::: "memory")
#define VMC0() asm volatile("s_waitcnt vmcnt(0)" ::: "memory")

// ---------------- weight fp32 -> bf16 convert ----------------
__global__ __launch_bounds__(256) void f2bf_kernel(const float* __restrict__ in,
                                                   short* __restrict__ out, int n4) {
  int i = blockIdx.x * 256 + threadIdx.x;
  if (i < n4) {
    float4 v = ((const float4*)in)[i];
    s4v o;
    o[0] = f2bf(v.x); o[1] = f2bf(v.y); o[2] = f2bf(v.z); o[3] = f2bf(v.w);
    ((s4v*)out)[i] = o;
  }
}

// ---------------- LayerNorm -> bf16 ----------------
__global__ __launch_bounds__(256) void ln_kernel(const float* __restrict__ x,
    const float* __restrict__ g, const float* __restrict__ b,
    short* __restrict__ h) {
  int row = blockIdx.x * 4 + (threadIdx.x >> 6);
  int lane = threadIdx.x & 63;
  const float* xr = x + (size_t)row * DIMC + lane * 8;
  float4 v0 = *(const float4*)xr;
  float4 v1 = *(const float4*)(xr + 4);
  float s = v0.x + v0.y + v0.z + v0.w + v1.x + v1.y + v1.z + v1.w;
  #pragma unroll
  for (int o = 32; o > 0; o >>= 1) s += __shfl_xor(s, o, 64);
  float mean = s * (1.0f / 512.0f);
  float d0 = v0.x-mean, d1 = v0.y-mean, d2 = v0.z-mean, d3 = v0.w-mean;
  float d4 = v1.x-mean, d5 = v1.y-mean, d6 = v1.z-mean, d7 = v1.w-mean;
  float vs = d0*d0+d1*d1+d2*d2+d3*d3+d4*d4+d5*d5+d6*d6+d7*d7;
  #pragma unroll
  for (int o = 32; o > 0; o >>= 1) vs += __shfl_xor(vs, o, 64);
  float rstd = rsqrtf(vs * (1.0f / 512.0f) + 1e-5f);
  const float* gp = g + lane * 8;
  const float* bp = b + lane * 8;
  float4 g0 = *(const float4*)gp, g1 = *(const float4*)(gp + 4);
  float4 b0 = *(const float4*)bp, b1 = *(const float4*)(bp + 4);
  s8v o;
  o[0] = f2bf(d0 * rstd * g0.x + b0.x);
  o[1] = f2bf(d1 * rstd * g0.y + b0.y);
  o[2] = f2bf(d2 * rstd * g0.z + b0.z);
  o[3] = f2bf(d3 * rstd * g0.w + b0.w);
  o[4] = f2bf(d4 * rstd * g1.x + b1.x);
  o[5] = f2bf(d5 * rstd * g1.y + b1.y);
  o[6] = f2bf(d6 * rstd * g1.z + b1.z);
  o[7] = f2bf(d7 * rstd * g1.w + b1.w);
  *(s8v*)(h + (size_t)row * DIMC + lane * 8) = o;
}

// ---------------- weight-stationary GEMM ----------------
// out[m,n] = sum_k A[m,k]*W[n,k] (+bias, epilogue).
// Block: 512 threads (8 waves), owns a 64-wide N panel; whole B panel
// (64 x K) resident in LDS (XOR-swizzled), staged ONCE. Each wave owns 64
// exclusive M rows per pass; A streamed global->reg with depth-2 rotation.
// NO barriers in the K-loop.
enum { EPI_BF16 = 0, EPI_RES_F32 = 1, EPI_GELU_BF16 = 2 };

template<int K, int NP, int EPI>
__global__ __launch_bounds__(512) void gemm_ws(
    const short* __restrict__ A, const short* __restrict__ Bm,
    const float* __restrict__ bias, const float* __restrict__ res,
    void* __restrict__ outp, int N, int nbx) {
  constexpr int NT = K / 64;    // 64-short K-tiles in LDS (8 KB each)
  constexpr int NK = K / 32;    // MFMA k-slices
  __shared__ __align__(16) short SB[NT * 4096];
  const int tid = threadIdx.x;
  const int wave = tid >> 6, lane = tid & 63;
  const int l15 = lane & 15, l4 = lane >> 4;
  // T1: XCD-aware swizzle (all grids % 8 == 0); consecutive swz share M-rows.
  const int nwg = gridDim.x, bid = blockIdx.x;
  const int swz = (bid & 7) * (nwg >> 3) + (bid >> 3);
  const int bx = swz % nbx, by = swz / nbx;
  const int n0 = bx * 64;

  // ---- stage whole B panel once (inverse-swizzled source, linear LDS dest) ----
  {
    const int r = tid >> 3, c = tid & 7;
    const short* src0 = Bm + (size_t)(n0 + r) * K + ((c ^ (r & 7)) << 3);
    #pragma unroll
    for (int t = 0; t < NT; ++t)
      load_lds16(src0 + t * 64, &SB[t * 4096 + ((tid & ~63) << 3)]);
    VMC0();
    BARX();
  }

  const int arow = wave * 64 + l15;   // + rt*16
  const int acol = l4 * 8;            // + ks*32

  #pragma unroll
  for (int p = 0; p < NP; ++p) {
    const int m0 = (by * NP + p) * 512;
    const short* Ab = A + (size_t)(m0 + arow) * K + acol;
    f4v acc[4][4] = {};
    s8v a[3][4];
    #pragma unroll
    for (int rt = 0; rt < 4; ++rt) a[0][rt] = *(const s8v*)(Ab + (size_t)rt * 16 * K);
    #pragma unroll
    for (int rt = 0; rt < 4; ++rt) a[1][rt] = *(const s8v*)(Ab + (size_t)rt * 16 * K + 32);

    #pragma unroll
    for (int ks = 0; ks < NK; ++ks) {
      if (ks + 2 < NK) {
        #pragma unroll
        for (int rt = 0; rt < 4; ++rt)
          a[(ks + 2) % 3][rt] = *(const s8v*)(Ab + (size_t)rt * 16 * K + (ks + 2) * 32);
      }
      s8v bf[4];
      #pragma unroll
      for (int ct = 0; ct < 4; ++ct) {
        const int nl = ct * 16 + l15;
        const int cc = (ks & 1) * 4 + l4;
        bf[ct] = *(const s8v*)&SB[(ks >> 1) * 4096 + (nl << 6) + ((cc ^ (nl & 7)) << 3)];
      }
      #pragma unroll
      for (int rt = 0; rt < 4; ++rt)
        #pragma unroll
        for (int ct = 0; ct < 4; ++ct)
          acc[rt][ct] = __builtin_amdgcn_mfma_f32_16x16x32_bf16(a[ks % 3][rt], bf[ct], acc[rt][ct], 0, 0, 0);
    }

    // ---- epilogue: C/D layout col=lane&15, row=(lane>>4)*4+r ----
    const int rbase = m0 + wave * 64 + (l4 << 2);
    #pragma unroll
    for (int rt = 0; rt < 4; ++rt) {
      #pragma unroll
      for (int ct = 0; ct < 4; ++ct) {
        const int n = n0 + ct * 16 + l15;
        const float bs = bias[n];
        #pragma unroll
        for (int r = 0; r < 4; ++r) {
          const int m = rbase + rt * 16 + r;
          const float v = acc[rt][ct][r] + bs;
          const size_t off = (size_t)m * N + n;
          if constexpr (EPI == EPI_RES_F32) {
            ((float*)outp)[off] = res[off] + v;
          } else if constexpr (EPI == EPI_GELU_BF16) {
            float gv = 0.5f * v * (1.0f + erff(v * 0.70710678118654752f));
            ((short*)outp)[off] = f2bf(gv);
          } else {
            ((short*)outp)[off] = f2bf(v);
          }
        }
      }
    }
  }
}

// ---------------- attention hop-bias precompute: battn[h][n][m] ----------------
__global__ __launch_bounds__(256) void attnbias_kernel(const float* __restrict__ H,
    const float* __restrict__ hop_logits, const float* __restrict__ rel_alpha,
    float* __restrict__ battn) {
  int t = threadIdx.x;
  for (int e = t; e < NHEADS * NTOK * NTOK; e += 256) {
    int h = e / (NTOK * NTOK);
    int nm = e - h * NTOK * NTOK;
    float l0 = hop_logits[h * 4 + 0], l1 = hop_logits[h * 4 + 1];
    float l2 = hop_logits[h * 4 + 2], l3 = hop_logits[h * 4 + 3];
    float mx = fmaxf(fmaxf(l0, l1), fmaxf(l2, l3));
    float e0 = expf(l0 - mx), e1 = expf(l1 - mx), e2 = expf(l2 - mx), e3 = expf(l3 - mx);
    float inv = 1.0f / (e0 + e1 + e2 + e3);
    float bsum = (e0 * H[0 * 289 + nm] + e1 * H[1 * 289 + nm] +
                  e2 * H[2 * 289 + nm] + e3 * H[3 * 289 + nm]) * inv;
    battn[e] = rel_alpha[h] * bsum;
  }
}

// ---------------- attention: one wave per (b,h) ----------------
__global__ __launch_bounds__(256) void attn_kernel(const short* __restrict__ qkv,
    const float* __restrict__ battn, short* __restrict__ out) {
  __shared__ __align__(16) short sq[4][NTOK * 64];
  __shared__ __align__(16) short sk[4][NTOK * 64];
  __shared__ __align__(16) short sv[4][NTOK * 64];
  __shared__ float sp[4][NTOK * 18];
  int w = threadIdx.x >> 6, lane = threadIdx.x & 63;
  int wid = blockIdx.x * 4 + w;
  int b = wid >> 3, h = wid & 7;

  for (int s = lane; s < NTOK * 8; s += 64) {
    int n = s >> 3, c8 = (s & 7) * 8;
    const short* rowp = qkv + (size_t)(b * NTOK + n) * 1536 + h * 64 + c8;
    *(s8v*)&sq[w][s * 8] = *(const s8v*)&rowp[0];
    *(s8v*)&sk[w][s * 8] = *(const s8v*)&rowp[512];
    *(s8v*)&sv[w][s * 8] = *(const s8v*)&rowp[1024];
  }
  __syncthreads();

  #pragma unroll
  for (int idx = 0; idx < 5; ++idx) {
    int e = idx * 64 + lane;
    int ec = e < 289 ? e : 288;
    int n = ec / 17, m = ec - n * 17;
    float acc = 0.f;
    #pragma unroll
    for (int c = 0; c < 8; ++c) {
      s8v qv = *(const s8v*)&sq[w][n * 64 + c * 8];
      s8v kv = *(const s8v*)&sk[w][m * 64 + c * 8];
      #pragma unroll
      for (int t = 0; t < 8; ++t) acc += bf2f(qv[t]) * bf2f(kv[t]);
    }
    if (e < 289) sp[w][n * 18 + m] = acc * 0.125f + battn[h * 289 + e];
  }
  __syncthreads();

  if (lane < NTOK) {
    float mx = -1e30f;
    #pragma unroll
    for (int m = 0; m < NTOK; ++m) mx = fmaxf(mx, sp[w][lane * 18 + m]);
    float pv[NTOK];
    float ssum = 0.f;
    #pragma unroll
    for (int m = 0; m < NTOK; ++m) { float ev = expf(sp[w][lane * 18 + m] - mx); pv[m] = ev; ssum += ev; }
    float inv = 1.0f / ssum;
    #pragma unroll
    for (int m = 0; m < NTOK; ++m) sp[w][lane * 18 + m] = pv[m] * inv;
  }
  __syncthreads();

  #pragma unroll
  for (int n = 0; n < NTOK; ++n) {
    float ov = 0.f;
    #pragma unroll
    for (int m = 0; m < NTOK; ++m) ov += sp[w][n * 18 + m] * bf2f(sv[w][m * 64 + lane]);
    out[(size_t)(b * NTOK + n) * DIMC + h * 64 + lane] = f2bf(ov);
  }
}

extern "C" void kernel_launch(void* const* d_in, const int* in_sizes, int n_in,
                              void* d_out, int out_size, void* d_ws, size_t ws_size,
                              hipStream_t stream) {
  const float* x_in       = (const float*)d_in[0];
  const float* Hstack     = (const float*)d_in[1];
  const float* hop_logits = (const float*)d_in[2];
  const float* rel_alpha  = (const float*)d_in[3];
  const float* qkv_w  = (const float*)d_in[4];
  const float* qkv_b  = (const float*)d_in[5];
  const float* proj_w = (const float*)d_in[6];
  const float* proj_b = (const float*)d_in[7];
  const float* ln1_g  = (const float*)d_in[8];
  const float* ln1_b  = (const float*)d_in[9];
  const float* ln2_g  = (const float*)d_in[10];
  const float* ln2_b  = (const float*)d_in[11];
  const float* fc1_w  = (const float*)d_in[12];
  const float* fc1_b  = (const float*)d_in[13];
  const float* fc2_w  = (const float*)d_in[14];
  const float* fc2_b  = (const float*)d_in[15];
  float* xout = (float*)d_out;

  // workspace layout
  short* wqkv  = (short*)d_ws;                       // 4*1536*512
  short* wproj = wqkv  + (size_t)4 * 1536 * 512;     // 4*512*512
  short* wfc1  = wproj + (size_t)4 * 512 * 512;      // 4*1024*512
  short* wfc2  = wfc1  + (size_t)4 * 1024 * 512;     // 4*512*1024
  float* battn = (float*)(wfc2 + (size_t)4 * 512 * 1024);  // 8*289 floats
  short* hbuf   = (short*)(battn + 2432);            // NROWS*512 bf16
  short* qkvbuf = hbuf + (size_t)NROWS * 512;        // NROWS*1536 bf16 (also fc1 hidden)

  {
    int n4;
    n4 = 4 * 1536 * 512 / 4;
    f2bf_kernel<<<dim3((n4 + 255) / 256), dim3(256), 0, stream>>>(qkv_w, wqkv, n4);
    n4 = 4 * 512 * 512 / 4;
    f2bf_kernel<<<dim3((n4 + 255) / 256), dim3(256), 0, stream>>>(proj_w, wproj, n4);
    n4 = 4 * 1024 * 512 / 4;
    f2bf_kernel<<<dim3((n4 + 255) / 256), dim3(256), 0, stream>>>(fc1_w, wfc1, n4);
    n4 = 4 * 512 * 1024 / 4;
    f2bf_kernel<<<dim3((n4 + 255) / 256), dim3(256), 0, stream>>>(fc2_w, wfc2, n4);
  }
  attnbias_kernel<<<dim3(1), dim3(256), 0, stream>>>(Hstack, hop_logits, rel_alpha, battn);

  const int LNBLK = NROWS / 4;      // 8704
  const dim3 B256(256), B512(512);
  // M passes: NROWS/512 = 68 per-pass chunks

  for (int d = 0; d < DEPTHL; ++d) {
    const float* xres = (d == 0) ? x_in : xout;
    // LN1 -> h (bf16)
    ln_kernel<<<dim3(LNBLK), B256, 0, stream>>>(xres, ln1_g + d * 512, ln1_b + d * 512, hbuf);
    // QKV GEMM -> qkvbuf bf16   (nbx=24, NP=2 -> 24*34=816 blocks)
    gemm_ws<512, 2, EPI_BF16><<<dim3(24 * 34), B512, 0, stream>>>(
        hbuf, wqkv + (size_t)d * 1536 * 512, qkv_b + d * 1536, nullptr, qkvbuf, 1536, 24);
    // attention -> hbuf
    attn_kernel<<<dim3(2048 * NHEADS / 4), B256, 0, stream>>>(qkvbuf, battn, hbuf);
    // proj GEMM + residual -> xout (fp32)   (nbx=8, NP=1 -> 544 blocks)
    gemm_ws<512, 1, EPI_RES_F32><<<dim3(8 * 68), B512, 0, stream>>>(
        hbuf, wproj + (size_t)d * 512 * 512, proj_b + d * 512, xres, xout, 512, 8);
    // LN2 -> h (bf16)
    ln_kernel<<<dim3(LNBLK), B256, 0, stream>>>(xout, ln2_g + d * 512, ln2_b + d * 512, hbuf);
    // fc1 GEMM + GELU -> qkvbuf (bf16 hidden)   (nbx=16, NP=2 -> 544 blocks)
    gemm_ws<512, 2, EPI_GELU_BF16><<<dim3(16 * 34), B512, 0, stream>>>(
        hbuf, wfc1 + (size_t)d * 1024 * 512, fc1_b + d * 1024, nullptr, qkvbuf, 1024, 16);
    // fc2 GEMM + residual -> xout (fp32)   (K=1024, nbx=8, NP=1 -> 544 blocks)
    gemm_ws<1024, 1, EPI_RES_F32><<<dim3(8 * 68), B512, 0, stream>>>(
        qkvbuf, wfc2 + (size_t)d * 512 * 1024, fc2_b + d * 512, xout, xout, 512, 8);
  }
}

// Round 5
// 1661.859 us; speedup vs baseline: 1.5763x; 1.5763x over previous
//
#include <hip/hip_runtime.h>

#define DEPTHL 4
#define NHEADS 8
#define DIMC 512
#define HIDDENC 1024
#define NTOK 17
#define NROWS (2048*NTOK)   // 34816

typedef __attribute__((ext_vector_type(8))) short s8v;
typedef __attribute__((ext_vector_type(4))) float f4v;
typedef __attribute__((ext_vector_type(4))) short s4v;

static __device__ __forceinline__ float bf2f(short s) {
  unsigned u = ((unsigned)(unsigned short)s) << 16;
  return __builtin_bit_cast(float, u);
}
static __device__ __forceinline__ short f2bf(float f) {
  unsigned u = __builtin_bit_cast(unsigned, f);
  u += 0x7fffu + ((u >> 16) & 1u);
  return (short)(u >> 16);
}

static __device__ __forceinline__ void load_lds16(const void* g, void* l) {
  __builtin_amdgcn_global_load_lds(
      (const __attribute__((address_space(1))) unsigned int*)g,
      (__attribute__((address_space(3))) unsigned int*)l, 16, 0, 0);
}

#define BARX() asm volatile("s_barrier" ::: "memory")
#define VMC(n) asm volatile("s_waitcnt vmcnt(" #n ")" ::: "memory")

// ---------------- weight fp32 -> bf16 convert ----------------
__global__ __launch_bounds__(256) void f2bf_kernel(const float* __restrict__ in,
                                                   short* __restrict__ out, int n4) {
  int i = blockIdx.x * 256 + threadIdx.x;
  if (i < n4) {
    float4 v = ((const float4*)in)[i];
    s4v o;
    o[0] = f2bf(v.x); o[1] = f2bf(v.y); o[2] = f2bf(v.z); o[3] = f2bf(v.w);
    ((s4v*)out)[i] = o;
  }
}

// ---------------- LayerNorm -> bf16 ----------------
__global__ __launch_bounds__(256) void ln_kernel(const float* __restrict__ x,
    const float* __restrict__ g, const float* __restrict__ b,
    short* __restrict__ h) {
  int row = blockIdx.x * 4 + (threadIdx.x >> 6);
  int lane = threadIdx.x & 63;
  const float* xr = x + (size_t)row * DIMC + lane * 8;
  float4 v0 = *(const float4*)xr;
  float4 v1 = *(const float4*)(xr + 4);
  float s = v0.x + v0.y + v0.z + v0.w + v1.x + v1.y + v1.z + v1.w;
  #pragma unroll
  for (int o = 32; o > 0; o >>= 1) s += __shfl_xor(s, o, 64);
  float mean = s * (1.0f / 512.0f);
  float d0 = v0.x-mean, d1 = v0.y-mean, d2 = v0.z-mean, d3 = v0.w-mean;
  float d4 = v1.x-mean, d5 = v1.y-mean, d6 = v1.z-mean, d7 = v1.w-mean;
  float vs = d0*d0+d1*d1+d2*d2+d3*d3+d4*d4+d5*d5+d6*d6+d7*d7;
  #pragma unroll
  for (int o = 32; o > 0; o >>= 1) vs += __shfl_xor(vs, o, 64);
  float rstd = rsqrtf(vs * (1.0f / 512.0f) + 1e-5f);
  const float* gp = g + lane * 8;
  const float* bp = b + lane * 8;
  float4 g0 = *(const float4*)gp, g1 = *(const float4*)(gp + 4);
  float4 b0 = *(const float4*)bp, b1 = *(const float4*)(bp + 4);
  s8v o;
  o[0] = f2bf(d0 * rstd * g0.x + b0.x);
  o[1] = f2bf(d1 * rstd * g0.y + b0.y);
  o[2] = f2bf(d2 * rstd * g0.z + b0.z);
  o[3] = f2bf(d3 * rstd * g0.w + b0.w);
  o[4] = f2bf(d4 * rstd * g1.x + b1.x);
  o[5] = f2bf(d5 * rstd * g1.y + b1.y);
  o[6] = f2bf(d6 * rstd * g1.z + b1.z);
  o[7] = f2bf(d7 * rstd * g1.w + b1.w);
  *(s8v*)(h + (size_t)row * DIMC + lane * 8) = o;
}

// ---------------- depth-3 pipelined GEMM ----------------
// out[m,n] = sum_k A[m,k]*W[n,k] (+bias, epilogue).
// 128x128 tile, BK=32, 4 LDS buffers (64 KB), 256 threads = 4 waves (2x2).
// Ledger: iter t stages tile t+3 (4 loads/thread); vmcnt(8) leaves {t+2,t+3}
// => tile t+1 landed; tile t landed at iter t-1. Buf (t+3)&3 == (t-1)&3,
// freed by the end-of-iter barrier of t-1. Two barriers per iter, counted
// vmcnt only (never a full drain in the main loop).
// LDS layout (packed-pair swizzle, conflict-free-enough: 2-way max):
//   element (r, g) [g = 8-short group 0..3] lives at lds_row = r>>1 (128B
//   rows), slot8 = (((r&1)<<2)|g) ^ (lds_row&7), byte = lds_row*128+slot8*16.
enum { EPI_BF16 = 0, EPI_RES_F32 = 1, EPI_GELU_BF16 = 2 };

template<int K, int EPI>
__global__ __launch_bounds__(256) void gemm_p4(
    const short* __restrict__ A, const short* __restrict__ Bm,
    const float* __restrict__ bias, const float* __restrict__ res,
    void* __restrict__ outp, int N, int nbx) {
  constexpr int NT = K / 32;
  __shared__ __align__(16) short SA[4][4096];   // 8 KB per buf: 128 rows x 32
  __shared__ __align__(16) short SB[4][4096];
  const int tid = threadIdx.x;
  const int wave = tid >> 6, lane = tid & 63;
  const int l15 = lane & 15, l4 = lane >> 4;
  // T1: XCD-aware swizzle; consecutive swz share the A (M) panel.
  const int nwg = gridDim.x, bid = blockIdx.x;
  const int swz = (bid & 7) * (nwg >> 3) + (bid >> 3);
  const int bx = swz % nbx, by = swz / nbx;
  const int m0 = by * 128, n0 = bx * 128;
  const int wr = wave >> 1, wc = wave & 1;    // wave-tile 64x64

  f4v acc[4][4] = {};

  // stage one 128x32 operand tile: 2 rounds of 4KB, linear LDS dest,
  // inverse-swizzled global source (same involution as the read side).
  auto stage1 = [&](const short* __restrict__ mat, int row0, int k0, short* buf) {
    #pragma unroll
    for (int q = 0; q < 2; ++q) {
      const int lr = q * 32 + (tid >> 3);           // lds_row 0..63
      const int sl = (tid & 7) ^ (lr & 7);          // unswizzled slot
      const short* src = mat + (size_t)(row0 + lr * 2 + (sl >> 2)) * K + k0 + ((sl & 3) << 3);
      load_lds16(src, buf + q * 2048 + ((tid & ~63) << 3));
    }
  };
  // swizzled fragment read: row r (within tile), k-group l4
  auto rdfrag = [&](const short* buf, int r) -> s8v {
    const int lr = r >> 1;
    const int sl = (((r & 1) << 2) | l4) ^ (lr & 7);
    return *(const s8v*)&buf[lr * 64 + (sl << 3)];
  };

  // prologue: stage tiles 0,1,2 (12 loads/thread in flight)
  stage1(A, m0, 0, SA[0]);  stage1(Bm, n0, 0, SB[0]);
  stage1(A, m0, 32, SA[1]); stage1(Bm, n0, 32, SB[1]);
  stage1(A, m0, 64, SA[2]); stage1(Bm, n0, 64, SB[2]);

  #pragma unroll
  for (int t = 0; t < NT; ++t) {
    if (t + 3 < NT) {
      stage1(A, m0, (t + 3) * 32, SA[(t + 3) & 3]);
      stage1(Bm, n0, (t + 3) * 32, SB[(t + 3) & 3]);
    }
    VMC(8);                       // tiles <= t+1 landed (t landed last iter)
    BARX();                       // all waves agree: buf[t&3] ready
    s8v af[4], bf[4];
    #pragma unroll
    for (int rt = 0; rt < 4; ++rt) af[rt] = rdfrag(SA[t & 3], wr * 64 + rt * 16 + l15);
    #pragma unroll
    for (int ct = 0; ct < 4; ++ct) bf[ct] = rdfrag(SB[t & 3], wc * 64 + ct * 16 + l15);
    __builtin_amdgcn_s_setprio(1);
    #pragma unroll
    for (int rt = 0; rt < 4; ++rt)
      #pragma unroll
      for (int ct = 0; ct < 4; ++ct)
        acc[rt][ct] = __builtin_amdgcn_mfma_f32_16x16x32_bf16(af[rt], bf[ct], acc[rt][ct], 0, 0, 0);
    __builtin_amdgcn_s_setprio(0);
    BARX();                       // protect buf[t&3] before iter t+1 restages it
  }

  // ---- epilogue: C/D layout col=lane&15, row=(lane>>4)*4+r ----
  #pragma unroll
  for (int rt = 0; rt < 4; ++rt) {
    #pragma unroll
    for (int ct = 0; ct < 4; ++ct) {
      const int n = n0 + wc * 64 + ct * 16 + l15;
      const float bs = bias[n];
      const int mb = m0 + wr * 64 + rt * 16 + (l4 << 2);
      #pragma unroll
      for (int r = 0; r < 4; ++r) {
        const int m = mb + r;
        const float v = acc[rt][ct][r] + bs;
        const size_t off = (size_t)m * N + n;
        if constexpr (EPI == EPI_RES_F32) {
          ((float*)outp)[off] = res[off] + v;
        } else if constexpr (EPI == EPI_GELU_BF16) {
          float gv = 0.5f * v * (1.0f + erff(v * 0.70710678118654752f));
          ((short*)outp)[off] = f2bf(gv);
        } else {
          ((short*)outp)[off] = f2bf(v);
        }
      }
    }
  }
}

// ---------------- attention hop-bias precompute: battn[h][n][m] ----------------
__global__ __launch_bounds__(256) void attnbias_kernel(const float* __restrict__ H,
    const float* __restrict__ hop_logits, const float* __restrict__ rel_alpha,
    float* __restrict__ battn) {
  int t = threadIdx.x;
  for (int e = t; e < NHEADS * NTOK * NTOK; e += 256) {
    int h = e / (NTOK * NTOK);
    int nm = e - h * NTOK * NTOK;
    float l0 = hop_logits[h * 4 + 0], l1 = hop_logits[h * 4 + 1];
    float l2 = hop_logits[h * 4 + 2], l3 = hop_logits[h * 4 + 3];
    float mx = fmaxf(fmaxf(l0, l1), fmaxf(l2, l3));
    float e0 = expf(l0 - mx), e1 = expf(l1 - mx), e2 = expf(l2 - mx), e3 = expf(l3 - mx);
    float inv = 1.0f / (e0 + e1 + e2 + e3);
    float bsum = (e0 * H[0 * 289 + nm] + e1 * H[1 * 289 + nm] +
                  e2 * H[2 * 289 + nm] + e3 * H[3 * 289 + nm]) * inv;
    battn[e] = rel_alpha[h] * bsum;
  }
}

// ---------------- attention: one wave per (b,h) ----------------
__global__ __launch_bounds__(256) void attn_kernel(const short* __restrict__ qkv,
    const float* __restrict__ battn, short* __restrict__ out) {
  __shared__ __align__(16) short sq[4][NTOK * 64];
  __shared__ __align__(16) short sk[4][NTOK * 64];
  __shared__ __align__(16) short sv[4][NTOK * 64];
  __shared__ float sp[4][NTOK * 18];
  int w = threadIdx.x >> 6, lane = threadIdx.x & 63;
  int wid = blockIdx.x * 4 + w;
  int b = wid >> 3, h = wid & 7;

  for (int s = lane; s < NTOK * 8; s += 64) {
    int n = s >> 3, c8 = (s & 7) * 8;
    const short* rowp = qkv + (size_t)(b * NTOK + n) * 1536 + h * 64 + c8;
    *(s8v*)&sq[w][s * 8] = *(const s8v*)&rowp[0];
    *(s8v*)&sk[w][s * 8] = *(const s8v*)&rowp[512];
    *(s8v*)&sv[w][s * 8] = *(const s8v*)&rowp[1024];
  }
  __syncthreads();

  #pragma unroll
  for (int idx = 0; idx < 5; ++idx) {
    int e = idx * 64 + lane;
    int ec = e < 289 ? e : 288;
    int n = ec / 17, m = ec - n * 17;
    float acc = 0.f;
    #pragma unroll
    for (int c = 0; c < 8; ++c) {
      s8v qv = *(const s8v*)&sq[w][n * 64 + c * 8];
      s8v kv = *(const s8v*)&sk[w][m * 64 + c * 8];
      #pragma unroll
      for (int t = 0; t < 8; ++t) acc += bf2f(qv[t]) * bf2f(kv[t]);
    }
    if (e < 289) sp[w][n * 18 + m] = acc * 0.125f + battn[h * 289 + e];
  }
  __syncthreads();

  if (lane < NTOK) {
    float mx = -1e30f;
    #pragma unroll
    for (int m = 0; m < NTOK; ++m) mx = fmaxf(mx, sp[w][lane * 18 + m]);
    float pv[NTOK];
    float ssum = 0.f;
    #pragma unroll
    for (int m = 0; m < NTOK; ++m) { float ev = expf(sp[w][lane * 18 + m] - mx); pv[m] = ev; ssum += ev; }
    float inv = 1.0f / ssum;
    #pragma unroll
    for (int m = 0; m < NTOK; ++m) sp[w][lane * 18 + m] = pv[m] * inv;
  }
  __syncthreads();

  #pragma unroll
  for (int n = 0; n < NTOK; ++n) {
    float ov = 0.f;
    #pragma unroll
    for (int m = 0; m < NTOK; ++m) ov += sp[w][n * 18 + m] * bf2f(sv[w][m * 64 + lane]);
    out[(size_t)(b * NTOK + n) * DIMC + h * 64 + lane] = f2bf(ov);
  }
}

extern "C" void kernel_launch(void* const* d_in, const int* in_sizes, int n_in,
                              void* d_out, int out_size, void* d_ws, size_t ws_size,
                              hipStream_t stream) {
  const float* x_in       = (const float*)d_in[0];
  const float* Hstack     = (const float*)d_in[1];
  const float* hop_logits = (const float*)d_in[2];
  const float* rel_alpha  = (const float*)d_in[3];
  const float* qkv_w  = (const float*)d_in[4];
  const float* qkv_b  = (const float*)d_in[5];
  const float* proj_w = (const float*)d_in[6];
  const float* proj_b = (const float*)d_in[7];
  const float* ln1_g  = (const float*)d_in[8];
  const float* ln1_b  = (const float*)d_in[9];
  const float* ln2_g  = (const float*)d_in[10];
  const float* ln2_b  = (const float*)d_in[11];
  const float* fc1_w  = (const float*)d_in[12];
  const float* fc1_b  = (const float*)d_in[13];
  const float* fc2_w  = (const float*)d_in[14];
  const float* fc2_b  = (const float*)d_in[15];
  float* xout = (float*)d_out;

  // workspace layout
  short* wqkv  = (short*)d_ws;                       // 4*1536*512
  short* wproj = wqkv  + (size_t)4 * 1536 * 512;     // 4*512*512
  short* wfc1  = wproj + (size_t)4 * 512 * 512;      // 4*1024*512
  short* wfc2  = wfc1  + (size_t)4 * 1024 * 512;     // 4*512*1024
  float* battn = (float*)(wfc2 + (size_t)4 * 512 * 1024);  // 8*289 floats
  short* hbuf   = (short*)(battn + 2432);            // NROWS*512 bf16
  short* qkvbuf = hbuf + (size_t)NROWS * 512;        // NROWS*1536 bf16 (also fc1 hidden)

  {
    int n4;
    n4 = 4 * 1536 * 512 / 4;
    f2bf_kernel<<<dim3((n4 + 255) / 256), dim3(256), 0, stream>>>(qkv_w, wqkv, n4);
    n4 = 4 * 512 * 512 / 4;
    f2bf_kernel<<<dim3((n4 + 255) / 256), dim3(256), 0, stream>>>(proj_w, wproj, n4);
    n4 = 4 * 1024 * 512 / 4;
    f2bf_kernel<<<dim3((n4 + 255) / 256), dim3(256), 0, stream>>>(fc1_w, wfc1, n4);
    n4 = 4 * 512 * 1024 / 4;
    f2bf_kernel<<<dim3((n4 + 255) / 256), dim3(256), 0, stream>>>(fc2_w, wfc2, n4);
  }
  attnbias_kernel<<<dim3(1), dim3(256), 0, stream>>>(Hstack, hop_logits, rel_alpha, battn);

  const int LNBLK = NROWS / 4;      // 8704
  const dim3 B256(256);
  const int MB = NROWS / 128;       // 272

  for (int d = 0; d < DEPTHL; ++d) {
    const float* xres = (d == 0) ? x_in : xout;
    // LN1 -> h (bf16)
    ln_kernel<<<dim3(LNBLK), B256, 0, stream>>>(xres, ln1_g + d * 512, ln1_b + d * 512, hbuf);
    // QKV GEMM -> qkvbuf bf16   (nbx=12 -> 3264 blocks)
    gemm_p4<512, EPI_BF16><<<dim3(12 * MB), B256, 0, stream>>>(
        hbuf, wqkv + (size_t)d * 1536 * 512, qkv_b + d * 1536, nullptr, qkvbuf, 1536, 12);
    // attention -> hbuf
    attn_kernel<<<dim3(2048 * NHEADS / 4), B256, 0, stream>>>(qkvbuf, battn, hbuf);
    // proj GEMM + residual -> xout (fp32)   (nbx=4 -> 1088 blocks)
    gemm_p4<512, EPI_RES_F32><<<dim3(4 * MB), B256, 0, stream>>>(
        hbuf, wproj + (size_t)d * 512 * 512, proj_b + d * 512, xres, xout, 512, 4);
    // LN2 -> h (bf16)
    ln_kernel<<<dim3(LNBLK), B256, 0, stream>>>(xout, ln2_g + d * 512, ln2_b + d * 512, hbuf);
    // fc1 GEMM + GELU -> qkvbuf (bf16 hidden)   (nbx=8 -> 2176 blocks)
    gemm_p4<512, EPI_GELU_BF16><<<dim3(8 * MB), B256, 0, stream>>>(
        hbuf, wfc1 + (size_t)d * 1024 * 512, fc1_b + d * 1024, nullptr, qkvbuf, 1024, 8);
    // fc2 GEMM + residual -> xout (fp32)   (K=1024, nbx=4 -> 1088 blocks)
    gemm_p4<1024, EPI_RES_F32><<<dim3(4 * MB), B256, 0, stream>>>(
        qkvbuf, wfc2 + (size_t)d * 512 * 1024, fc2_b + d * 512, xout, xout, 512, 4);
  }
}